// Round 11
// baseline (168.630 us; speedup 1.0000x reference)
//
#include <hip/hip_runtime.h>

typedef _Float16 half_t;
typedef _Float16 h2 __attribute__((ext_vector_type(2)));
typedef unsigned int uint32;

#define K_ 100
#define F_ 128
#define E_ 200
#define CHUNK 20    // e per chunk
#define NCH 10      // chunks
#define XSU 68      // xs/wc row stride in uints (64 data + 4 pad; 16B-aligned rows)
#define PCS 22      // Lc/Rc row stride in floats (20 data + 2 pad)

__device__ __forceinline__ h2 bch2(uint32 u) { return __builtin_bit_cast(h2, u); }

#if defined(__has_builtin)
#if __has_builtin(__builtin_amdgcn_fdot2)
#define FDOT2(a, b, c) __builtin_amdgcn_fdot2((a), (b), (c), false)
#endif
#endif
#ifndef FDOT2
#define FDOT2(a, b, c) fmaf((float)(a).y, (float)(b).y, fmaf((float)(a).x, (float)(b).x, (c)))
#endif

// K1: per (half-batch h, batch b): projections (fdot2, f32 accum) -> pair sweep
// -> logits -> softmax -> att stored as FLOAT32 into the d_out rows this block
// owns (att[i,j] at out[(b*100+i)*128 + j], j<100). No workspace.
// INPUTS float32, OUTPUT float32 (per reference — verified by R8/R9/R10 triangulation).
__global__ __launch_bounds__(640) void k_att(
    const float* __restrict__ x,      // (64,100,128) f32
    const float* __restrict__ W,      // (256,200) f32
    const float* __restrict__ bvec,   // (200,) f32
    const float* __restrict__ avec,   // (200,) f32
    const float* __restrict__ bias,   // (100,100) f32
    float* __restrict__ out)          // (64,100,128) f32
{
  const int t  = threadIdx.x;
  const int h  = blockIdx.x;        // 0..1 -> i0 = 50h
  const int b  = blockIdx.y;        // 0..63
  const int i0 = 50 * h;

  __shared__ __align__(16) uint32 xs[K_ * XSU];   // fp16-pair x[b]   27,200 B
  __shared__ __align__(16) uint32 wc[40 * XSU];   // fp16-pair W chunk 10,880 B
  __shared__ __align__(16) float  Rc[K_ * PCS];   // R' chunk f32       8,800 B
  __shared__ __align__(16) float  Lc[50 * PCS];   // L  chunk f32       4,400 B
  __shared__ float scratch[640];                  //                    2,560 B
  __shared__ float rowmaxA[50];
  __shared__ float rowinvA[50];
  __shared__ float ah[CHUNK];
  __shared__ float aLt[50];
  __shared__ float aRt[K_];                        // total ~55 KB

  // stage x[b] as fp16 pairs (f32 -> fp16, rel err ~5e-4)
  {
    const float2* xg = (const float2*)(x + (size_t)b * K_ * F_);
    for (int u = t; u < K_ * F_ / 2; u += 640) {
      int row = u >> 6, f2 = u & 63;
      float2 v = xg[u];
      h2 p; p.x = (half_t)v.x; p.y = (half_t)v.y;
      xs[row * XSU + f2] = __builtin_bit_cast(uint32, p);
    }
    if (t < 50) aLt[t] = 0.f;
    if (t < K_) aRt[t] = 0.f;
  }
  __syncthreads();

  const int ti = t % 25, tj = t / 25;   // pair-sweep mapping (t<625)
  float acc2[2][4];
  #pragma unroll
  for (int r = 0; r < 2; ++r)
    #pragma unroll
    for (int s = 0; s < 4; ++s) acc2[r][s] = 0.f;

  for (int c = 0; c < NCH; ++c) {
    const int e0 = c * CHUNK;

    // stage W chunk as fp16 f-pairs. wc row cidx: cidx<20 -> W2 col e0+cidx (R),
    // cidx in [20,40) -> W1 col e0+cidx-20 (L).
    for (int u = t; u < 40 * 64; u += 640) {
      int cidx = u >> 6, f2 = u & 63, f = 2 * f2;
      const float* wp = W + (cidx < CHUNK ? (size_t)F_ * E_ : (size_t)0)
                          + (e0 + (cidx < CHUNK ? cidx : cidx - CHUNK));
      h2 p; p.x = (half_t)wp[(size_t)f * E_];
            p.y = (half_t)wp[(size_t)(f + 1) * E_];
      wc[cidx * XSU + f2] = __builtin_bit_cast(uint32, p);
    }
    if (t < CHUNK) ah[t] = avec[e0 + t];
    __syncthreads();

    // P1: 750 2x2 tiles over unified rows [0,100)=R, [100,150)=L ; cols 20
    for (int u = t; u < 750; u += 640) {
      int rt = u / 10, ct = u - rt * 10;
      int dr = 2 * rt, cc = 2 * ct;
      bool isR = (dr < 100);
      int xr0 = isR ? dr : (i0 + dr - 100);
      const uint32* X0 = xs + xr0 * XSU;
      const uint32* X1 = X0 + XSU;
      const uint32* Wa = wc + ((isR ? 0 : CHUNK) + cc) * XSU;
      const uint32* Wb = Wa + XSU;
      float a00 = 0.f, a01 = 0.f, a10 = 0.f, a11 = 0.f;
      #pragma unroll
      for (int q = 0; q < 16; ++q) {
        uint4 xa = *(const uint4*)(X0 + 4 * q);
        uint4 xb = *(const uint4*)(X1 + 4 * q);
        uint4 wa = *(const uint4*)(Wa + 4 * q);
        uint4 wb = *(const uint4*)(Wb + 4 * q);
        a00 = FDOT2(bch2(xa.x), bch2(wa.x), a00);
        a00 = FDOT2(bch2(xa.y), bch2(wa.y), a00);
        a00 = FDOT2(bch2(xa.z), bch2(wa.z), a00);
        a00 = FDOT2(bch2(xa.w), bch2(wa.w), a00);
        a01 = FDOT2(bch2(xa.x), bch2(wb.x), a01);
        a01 = FDOT2(bch2(xa.y), bch2(wb.y), a01);
        a01 = FDOT2(bch2(xa.z), bch2(wb.z), a01);
        a01 = FDOT2(bch2(xa.w), bch2(wb.w), a01);
        a10 = FDOT2(bch2(xb.x), bch2(wa.x), a10);
        a10 = FDOT2(bch2(xb.y), bch2(wa.y), a10);
        a10 = FDOT2(bch2(xb.z), bch2(wa.z), a10);
        a10 = FDOT2(bch2(xb.w), bch2(wa.w), a10);
        a11 = FDOT2(bch2(xb.x), bch2(wb.x), a11);
        a11 = FDOT2(bch2(xb.y), bch2(wb.y), a11);
        a11 = FDOT2(bch2(xb.z), bch2(wb.z), a11);
        a11 = FDOT2(bch2(xb.w), bch2(wb.w), a11);
      }
      if (isR) {
        float b0 = bvec[e0 + cc], b1 = bvec[e0 + cc + 1];
        Rc[dr * PCS + cc]           = a00 + b0;
        Rc[dr * PCS + cc + 1]       = a01 + b1;
        Rc[(dr + 1) * PCS + cc]     = a10 + b0;
        Rc[(dr + 1) * PCS + cc + 1] = a11 + b1;
      } else {
        int lr = dr - 100;
        Lc[lr * PCS + cc]           = a00;
        Lc[lr * PCS + cc + 1]       = a01;
        Lc[(lr + 1) * PCS + cc]     = a10;
        Lc[(lr + 1) * PCS + cc + 1] = a11;
      }
    }
    __syncthreads();

    // P2: aR/aL partials from the SAME stored f32 values (exact decomposition)
    if (t < 150) {
      float s = 0.f;
      if (t < K_) {
        for (int e = 0; e < CHUNK; ++e) s = fmaf(ah[e], Rc[t * PCS + e], s);
        aRt[t] += s;
      } else {
        int i = t - K_;
        for (int e = 0; e < CHUNK; ++e) s = fmaf(ah[e], Lc[i * PCS + e], s);
        aLt[i] += s;
      }
    }

    // P3: pair sweep c[i,j] += sum_e a_e * min(L+R', 0)
    if (t < 625) {
      const float* L0 = Lc + ti * PCS;
      const float* L1 = Lc + (ti + 25) * PCS;
      const float* R0 = Rc + tj * PCS;
      const float* R1 = Rc + (tj + 25) * PCS;
      const float* R2 = Rc + (tj + 50) * PCS;
      const float* R3 = Rc + (tj + 75) * PCS;
      #pragma unroll
      for (int cp = 0; cp < CHUNK / 2; ++cp) {
        float2 av = *(const float2*)(ah + 2 * cp);
        float2 l0 = *(const float2*)(L0 + 2 * cp);
        float2 l1 = *(const float2*)(L1 + 2 * cp);
        float2 r0 = *(const float2*)(R0 + 2 * cp);
        float2 r1 = *(const float2*)(R1 + 2 * cp);
        float2 r2 = *(const float2*)(R2 + 2 * cp);
        float2 r3 = *(const float2*)(R3 + 2 * cp);
        acc2[0][0] = fmaf(av.x, fminf(l0.x + r0.x, 0.f), acc2[0][0]);
        acc2[0][0] = fmaf(av.y, fminf(l0.y + r0.y, 0.f), acc2[0][0]);
        acc2[0][1] = fmaf(av.x, fminf(l0.x + r1.x, 0.f), acc2[0][1]);
        acc2[0][1] = fmaf(av.y, fminf(l0.y + r1.y, 0.f), acc2[0][1]);
        acc2[0][2] = fmaf(av.x, fminf(l0.x + r2.x, 0.f), acc2[0][2]);
        acc2[0][2] = fmaf(av.y, fminf(l0.y + r2.y, 0.f), acc2[0][2]);
        acc2[0][3] = fmaf(av.x, fminf(l0.x + r3.x, 0.f), acc2[0][3]);
        acc2[0][3] = fmaf(av.y, fminf(l0.y + r3.y, 0.f), acc2[0][3]);
        acc2[1][0] = fmaf(av.x, fminf(l1.x + r0.x, 0.f), acc2[1][0]);
        acc2[1][0] = fmaf(av.y, fminf(l1.y + r0.y, 0.f), acc2[1][0]);
        acc2[1][1] = fmaf(av.x, fminf(l1.x + r1.x, 0.f), acc2[1][1]);
        acc2[1][1] = fmaf(av.y, fminf(l1.y + r1.y, 0.f), acc2[1][1]);
        acc2[1][2] = fmaf(av.x, fminf(l1.x + r2.x, 0.f), acc2[1][2]);
        acc2[1][2] = fmaf(av.y, fminf(l1.y + r2.y, 0.f), acc2[1][2]);
        acc2[1][3] = fmaf(av.x, fminf(l1.x + r3.x, 0.f), acc2[1][3]);
        acc2[1][3] = fmaf(av.y, fminf(l1.y + r3.y, 0.f), acc2[1][3]);
      }
    }
    __syncthreads();   // protect wc/Rc/Lc/ah restage next chunk
  }

  // logits (clamped -> always finite)
  float v[2][4];
  if (t < 625) {
    #pragma unroll
    for (int r = 0; r < 2; ++r)
      #pragma unroll
      for (int s = 0; s < 4; ++s) {
        int i = ti + 25 * r, j = tj + 25 * s;
        float lv = aLt[i] + aRt[j] + bias[(i0 + i) * K_ + j] - 0.8f * acc2[r][s];
        v[r][s] = fminf(fmaxf(lv, -30000.f), 30000.f);
      }
  }

  // row max (rows 0..49 local; partials of row ti+25r live in threads t%25==ti)
  for (int r = 0; r < 2; ++r) {
    float m = -3.0e38f;
    if (t < 625) {
      #pragma unroll
      for (int s = 0; s < 4; ++s) m = fmaxf(m, v[r][s]);
    }
    scratch[t] = m;
    __syncthreads();
    if (t < 25) {
      float mm = scratch[t];
      for (int k = 1; k < 25; ++k) mm = fmaxf(mm, scratch[t + 25 * k]);
      rowmaxA[t + 25 * r] = mm;
    }
    __syncthreads();
  }
  // row sum of exp
  for (int r = 0; r < 2; ++r) {
    float ssum = 0.f;
    if (t < 625) {
      float m = rowmaxA[ti + 25 * r];
      #pragma unroll
      for (int s = 0; s < 4; ++s) ssum += __expf(v[r][s] - m);
    }
    scratch[t] = ssum;
    __syncthreads();
    if (t < 25) {
      float s2 = 0.f;
      for (int k = 0; k < 25; ++k) s2 += scratch[t + 25 * k];
      rowinvA[t + 25 * r] = 1.f / s2;
    }
    __syncthreads();
  }
  // att -> FLOAT32 -> d_out (block-owned rows only)
  if (t < 625) {
    #pragma unroll
    for (int r = 0; r < 2; ++r) {
      float m = rowmaxA[ti + 25 * r], inv = rowinvA[ti + 25 * r];
      #pragma unroll
      for (int s = 0; s < 4; ++s) {
        int i = ti + 25 * r, j = tj + 25 * s;
        float att = __expf(v[r][s] - m) * inv;
        out[((size_t)(b * K_ + i0 + i)) * F_ + j] = att;
      }
    }
  }
}

// K2: h = sigmoid(att @ x), FLOAT32 out. Block (i,b) reads ONLY its own att row
// from d_out, then overwrites that full 128-float row.
__global__ __launch_bounds__(128) void k_out(
    const float* __restrict__ x, float* __restrict__ out)
{
  const int i = blockIdx.x, b = blockIdx.y, f = threadIdx.x;
  __shared__ float att_s[K_];
  float* row = out + ((size_t)(b * K_ + i)) * F_;
  if (f < K_) att_s[f] = row[f];
  __syncthreads();
  const float* xb = x + (size_t)b * K_ * F_ + f;
  float z = 0.f;
  #pragma unroll 4
  for (int j = 0; j < K_; ++j)
    z = fmaf(att_s[j], xb[(size_t)j * F_], z);
  float hh = 1.f / (1.f + __expf(-z));
  row[f] = hh;
}

extern "C" void kernel_launch(void* const* d_in, const int* in_sizes, int n_in,
                              void* d_out, int out_size, void* d_ws, size_t ws_size,
                              hipStream_t stream)
{
  const float* x    = (const float*)d_in[0];   // (64,100,128) f32
  const float* W    = (const float*)d_in[1];   // (256,200) f32
  const float* bvec = (const float*)d_in[2];   // (200,) f32
  const float* avec = (const float*)d_in[3];   // (200,) f32
  const float* bias = (const float*)d_in[4];   // (100,100) f32
  float* out = (float*)d_out;                  // (64,100,128) f32

  k_att<<<dim3(2, 64), dim3(640), 0, stream>>>(x, W, bvec, avec, bias, out);
  k_out<<<dim3(K_, 64), dim3(128), 0, stream>>>(x, out);
}

// Round 12
// 137.175 us; speedup vs baseline: 1.2293x; 1.2293x over previous
//
#include <hip/hip_runtime.h>

typedef _Float16 half_t;
typedef _Float16 h2 __attribute__((ext_vector_type(2)));
typedef unsigned int uint32;

#define K_ 100
#define F_ 128
#define E_ 200
#define CHUNK 20    // e per chunk
#define NCH 10      // chunks
#define XSU 68      // xs/wc row stride in uints (64 data + 4 pad; 16B-aligned rows)
#define PCS 22      // Lc/Rc row stride in floats (20 data + 2 pad)
#define IT 25       // i-rows per block

__device__ __forceinline__ h2 bch2(uint32 u) { return __builtin_bit_cast(h2, u); }

#if defined(__has_builtin)
#if __has_builtin(__builtin_amdgcn_fdot2)
#define FDOT2(a, b, c) __builtin_amdgcn_fdot2((a), (b), (c), false)
#endif
#endif
#ifndef FDOT2
#define FDOT2(a, b, c) fmaf((float)(a).y, (float)(b).y, fmaf((float)(a).x, (float)(b).x, (c)))
#endif

// Fully fused: projections (fdot2) -> pair sweep -> logits -> softmax -> output
// GEMM + sigmoid, one block per (i-tile of 25, batch). x stays in LDS for the
// epilogue (kills the old k_out's 327 MB of cache re-reads). f32 in / f32 out.
__global__ __launch_bounds__(640) void k_fused(
    const float* __restrict__ x,      // (64,100,128) f32
    const float* __restrict__ W,      // (256,200) f32
    const float* __restrict__ bvec,   // (200,) f32
    const float* __restrict__ avec,   // (200,) f32
    const float* __restrict__ bias,   // (100,100) f32
    float* __restrict__ out)          // (64,100,128) f32
{
  const int t  = threadIdx.x;
  const int i0 = (int)blockIdx.x * IT;  // 0,25,50,75
  const int b  = (int)blockIdx.y;       // 0..63

  __shared__ __align__(16) uint32 xs[K_ * XSU];   // fp16-pair x[b]   27,200 B
  __shared__ __align__(16) uint32 wc[40 * XSU];   // W chunk / att     10,880 B
  __shared__ __align__(16) float  Rc[K_ * PCS];   // R' chunk f32       8,800 B
  __shared__ __align__(16) float  Lc[IT * PCS];   // L  chunk f32       2,200 B
  __shared__ float scratch[640];                  //                    2,560 B
  __shared__ float rowmaxA[IT];
  __shared__ float rowinvA[IT];
  __shared__ float ah[CHUNK];
  __shared__ float aLt[IT];
  __shared__ float aRt[K_];                        // total ~52.4 KB

  // stage x[b] as fp16 pairs
  {
    const float2* xg = (const float2*)(x + (size_t)b * K_ * F_);
    for (int u = t; u < K_ * F_ / 2; u += 640) {
      int row = u >> 6, f2 = u & 63;
      float2 v = xg[u];
      h2 p; p.x = (half_t)v.x; p.y = (half_t)v.y;
      xs[row * XSU + f2] = __builtin_bit_cast(uint32, p);
    }
    if (t < IT) aLt[t] = 0.f;
    if (t < K_) aRt[t] = 0.f;
  }
  __syncthreads();

  const int ti = t % 25, tj = t / 25;   // pair-sweep map (t<625): i=ti, j=tj+25s
  float acc[4];
  #pragma unroll
  for (int s = 0; s < 4; ++s) acc[s] = 0.f;

  for (int c = 0; c < NCH; ++c) {
    const int e0 = c * CHUNK;

    // stage W chunk fp16 f-pairs. wc row cidx: [0,20)=W2 col e0+cidx (R);
    // [20,40)=W1 col e0+cidx-20 (L).
    for (int u = t; u < 40 * 64; u += 640) {
      int cidx = u >> 6, f2 = u & 63, f = 2 * f2;
      const float* wp = W + (cidx < CHUNK ? (size_t)F_ * E_ : (size_t)0)
                          + (e0 + (cidx < CHUNK ? cidx : cidx - CHUNK));
      h2 p; p.x = (half_t)wp[(size_t)f * E_];
            p.y = (half_t)wp[(size_t)(f + 1) * E_];
      wc[cidx * XSU + f2] = __builtin_bit_cast(uint32, p);
    }
    if (t < CHUNK) ah[t] = avec[e0 + t];
    __syncthreads();

    // P1: 630 2x2 tiles over unified rows [0,100)=R, [100,125)=L ; cols 20
    for (int u = t; u < 630; u += 640) {
      int rt = u / 10, ct = u - rt * 10;
      int dr = 2 * rt, cc = 2 * ct;       // dr 0..124 (dr,dr+1), cc 0..18
      bool isR = (dr < 100);
      bool row1ok = isR || (dr - 100 + 1 < IT);
      int xr0 = isR ? dr : (i0 + dr - 100);
      int xr1 = row1ok ? xr0 + 1 : xr0;   // clamp: no OOB xs read
      const uint32* X0 = xs + xr0 * XSU;
      const uint32* X1 = xs + xr1 * XSU;
      const uint32* Wa = wc + ((isR ? 0 : CHUNK) + cc) * XSU;
      const uint32* Wb = Wa + XSU;
      float a00 = 0.f, a01 = 0.f, a10 = 0.f, a11 = 0.f;
      #pragma unroll
      for (int q = 0; q < 16; ++q) {
        uint4 xa = *(const uint4*)(X0 + 4 * q);
        uint4 xb = *(const uint4*)(X1 + 4 * q);
        uint4 wa = *(const uint4*)(Wa + 4 * q);
        uint4 wb = *(const uint4*)(Wb + 4 * q);
        a00 = FDOT2(bch2(xa.x), bch2(wa.x), a00);
        a00 = FDOT2(bch2(xa.y), bch2(wa.y), a00);
        a00 = FDOT2(bch2(xa.z), bch2(wa.z), a00);
        a00 = FDOT2(bch2(xa.w), bch2(wa.w), a00);
        a01 = FDOT2(bch2(xa.x), bch2(wb.x), a01);
        a01 = FDOT2(bch2(xa.y), bch2(wb.y), a01);
        a01 = FDOT2(bch2(xa.z), bch2(wb.z), a01);
        a01 = FDOT2(bch2(xa.w), bch2(wb.w), a01);
        a10 = FDOT2(bch2(xb.x), bch2(wa.x), a10);
        a10 = FDOT2(bch2(xb.y), bch2(wa.y), a10);
        a10 = FDOT2(bch2(xb.z), bch2(wa.z), a10);
        a10 = FDOT2(bch2(xb.w), bch2(wa.w), a10);
        a11 = FDOT2(bch2(xb.x), bch2(wb.x), a11);
        a11 = FDOT2(bch2(xb.y), bch2(wb.y), a11);
        a11 = FDOT2(bch2(xb.z), bch2(wb.z), a11);
        a11 = FDOT2(bch2(xb.w), bch2(wb.w), a11);
      }
      if (isR) {
        float b0 = bvec[e0 + cc], b1 = bvec[e0 + cc + 1];
        Rc[dr * PCS + cc]           = a00 + b0;
        Rc[dr * PCS + cc + 1]       = a01 + b1;
        Rc[(dr + 1) * PCS + cc]     = a10 + b0;
        Rc[(dr + 1) * PCS + cc + 1] = a11 + b1;
      } else {
        int lr = dr - 100;
        Lc[lr * PCS + cc]     = a00;
        Lc[lr * PCS + cc + 1] = a01;
        if (row1ok) {
          Lc[(lr + 1) * PCS + cc]     = a10;
          Lc[(lr + 1) * PCS + cc + 1] = a11;
        }
      }
    }
    __syncthreads();

    // P2: aR/aL partials from the SAME stored f32 values
    if (t < K_) {
      float s = 0.f;
      for (int e = 0; e < CHUNK; ++e) s = fmaf(ah[e], Rc[t * PCS + e], s);
      aRt[t] += s;
    } else if (t < K_ + IT) {
      int i = t - K_;
      float s = 0.f;
      for (int e = 0; e < CHUNK; ++e) s = fmaf(ah[e], Lc[i * PCS + e], s);
      aLt[i] += s;
    }

    // P3: pair sweep c[i,j] += sum_e a_e * min(L+R', 0)
    if (t < 625) {
      const float* Lp = Lc + ti * PCS;
      const float* R0 = Rc + tj * PCS;
      const float* R1 = Rc + (tj + 25) * PCS;
      const float* R2 = Rc + (tj + 50) * PCS;
      const float* R3 = Rc + (tj + 75) * PCS;
      #pragma unroll
      for (int cp = 0; cp < CHUNK / 2; ++cp) {
        float2 av = *(const float2*)(ah + 2 * cp);
        float2 lv = *(const float2*)(Lp + 2 * cp);
        float2 r0 = *(const float2*)(R0 + 2 * cp);
        float2 r1 = *(const float2*)(R1 + 2 * cp);
        float2 r2 = *(const float2*)(R2 + 2 * cp);
        float2 r3 = *(const float2*)(R3 + 2 * cp);
        acc[0] = fmaf(av.x, fminf(lv.x + r0.x, 0.f), acc[0]);
        acc[0] = fmaf(av.y, fminf(lv.y + r0.y, 0.f), acc[0]);
        acc[1] = fmaf(av.x, fminf(lv.x + r1.x, 0.f), acc[1]);
        acc[1] = fmaf(av.y, fminf(lv.y + r1.y, 0.f), acc[1]);
        acc[2] = fmaf(av.x, fminf(lv.x + r2.x, 0.f), acc[2]);
        acc[2] = fmaf(av.y, fminf(lv.y + r2.y, 0.f), acc[2]);
        acc[3] = fmaf(av.x, fminf(lv.x + r3.x, 0.f), acc[3]);
        acc[3] = fmaf(av.y, fminf(lv.y + r3.y, 0.f), acc[3]);
      }
    }
    __syncthreads();   // protect wc/Rc/Lc/ah restage (and att overlay at end)
  }

  // logits (clamped -> finite)
  float v[4];
  if (t < 625) {
    #pragma unroll
    for (int s = 0; s < 4; ++s) {
      int j = tj + 25 * s;
      float lv = aLt[ti] + aRt[j] + bias[(i0 + ti) * K_ + j] - 0.8f * acc[s];
      v[s] = fminf(fmaxf(lv, -30000.f), 30000.f);
    }
  }

  // softmax: row ti's 25 partials live at threads t%25==ti
  {
    float m = -3.0e38f;
    if (t < 625) {
      #pragma unroll
      for (int s = 0; s < 4; ++s) m = fmaxf(m, v[s]);
    }
    scratch[t] = m;
    __syncthreads();
    if (t < IT) {
      float mm = scratch[t];
      for (int k = 1; k < 25; ++k) mm = fmaxf(mm, scratch[t + 25 * k]);
      rowmaxA[t] = mm;
    }
    __syncthreads();
    float ssum = 0.f;
    if (t < 625) {
      float m2 = rowmaxA[ti];
      #pragma unroll
      for (int s = 0; s < 4; ++s) ssum += __expf(v[s] - m2);
    }
    scratch[t] = ssum;
    __syncthreads();
    if (t < IT) {
      float s2 = 0.f;
      for (int k = 0; k < 25; ++k) s2 += scratch[t + 25 * k];
      rowinvA[t] = 1.f / s2;
    }
    __syncthreads();
  }

  // att (f32) overlays wc (dead after last chunk): 25x100 = 10,000 B <= 10,880
  float* att = (float*)wc;
  if (t < 625) {
    float m = rowmaxA[ti], inv = rowinvA[ti];
    #pragma unroll
    for (int s = 0; s < 4; ++s)
      att[ti * K_ + (tj + 25 * s)] = __expf(v[s] - m) * inv;
  }
  __syncthreads();

  // epilogue: h = sigmoid(att @ x) using the fp16 xs already in LDS.
  // thread -> (f-pair f2, row-group ig): rows ig, ig+10, ig+20(ig<5).
  {
    const int f2 = t & 63, ig = t >> 6;     // ig 0..9 (wave-uniform)
    float z0a = 0.f, z0b = 0.f, z1a = 0.f, z1b = 0.f, z2a = 0.f, z2b = 0.f;
    const bool has3 = (ig < 5);
    for (int j = 0; j < K_; ++j) {
      h2 p = bch2(xs[j * XSU + f2]);
      float xa = (float)p.x, xb = (float)p.y;
      float a0 = att[ig * K_ + j];
      float a1 = att[(ig + 10) * K_ + j];
      z0a = fmaf(a0, xa, z0a); z0b = fmaf(a0, xb, z0b);
      z1a = fmaf(a1, xa, z1a); z1b = fmaf(a1, xb, z1b);
      if (has3) {
        float a2 = att[(ig + 20) * K_ + j];
        z2a = fmaf(a2, xa, z2a); z2b = fmaf(a2, xb, z2b);
      }
    }
    float2* op = (float2*)out;
    size_t rbase = (size_t)(b * K_ + i0);
    float2 h0; h0.x = 1.f / (1.f + __expf(-z0a)); h0.y = 1.f / (1.f + __expf(-z0b));
    op[(rbase + ig) * 64 + f2] = h0;
    float2 h1; h1.x = 1.f / (1.f + __expf(-z1a)); h1.y = 1.f / (1.f + __expf(-z1b));
    op[(rbase + ig + 10) * 64 + f2] = h1;
    if (has3) {
      float2 h2v; h2v.x = 1.f / (1.f + __expf(-z2a)); h2v.y = 1.f / (1.f + __expf(-z2b));
      op[(rbase + ig + 20) * 64 + f2] = h2v;
    }
  }
}

extern "C" void kernel_launch(void* const* d_in, const int* in_sizes, int n_in,
                              void* d_out, int out_size, void* d_ws, size_t ws_size,
                              hipStream_t stream)
{
  const float* x    = (const float*)d_in[0];   // (64,100,128) f32
  const float* W    = (const float*)d_in[1];   // (256,200) f32
  const float* bvec = (const float*)d_in[2];   // (200,) f32
  const float* avec = (const float*)d_in[3];   // (200,) f32
  const float* bias = (const float*)d_in[4];   // (100,100) f32
  float* out = (float*)d_out;                  // (64,100,128) f32

  k_fused<<<dim3(4, 64), dim3(640), 0, stream>>>(x, W, bvec, avec, bias, out);
}

// Round 14
// 124.640 us; speedup vs baseline: 1.3529x; 1.1006x over previous
//
#include <hip/hip_runtime.h>

typedef _Float16 half_t;
typedef _Float16 h2 __attribute__((ext_vector_type(2)));
typedef unsigned int uint32;

#define K_ 100
#define F_ 128
#define E_ 200

#if defined(__has_builtin)
#if __has_builtin(__builtin_amdgcn_fdot2)
#define FDOT2(a,b,c) __builtin_amdgcn_fdot2((a),(b),(c),false)
#endif
#endif
#ifndef FDOT2
#define FDOT2(a,b,c) fmaf((float)(a).y,(float)(b).y, fmaf((float)(a).x,(float)(b).x,(c)))
#endif

__device__ __forceinline__ h2 bch2(uint32 u){ return __builtin_bit_cast(h2,u); }
__device__ __forceinline__ uint32 pkh2(float a, float b){
  h2 p; p.x=(half_t)a; p.y=(half_t)b; return __builtin_bit_cast(uint32,p);
}

// ws layout (uints): Lh[6400][100] @0 ; Rh[6400][100] @640000 ; ah2[100] @1280000
// total 5.12 MB
#define LH_OFF 0
#define RH_OFF 640000
#define AH_OFF 1280000

// K1: L = x@W1, R' = x@W2 + b  -> fp16 h2 pairs (e-major) in ws. Computed ONCE
// (R12 recomputed R x4). grid 256 x 256thr, 25 rows/block, 4x4 fdot2 tiles,
// W transposed via coalesced f32 staging (no strided global reads).
__global__ __launch_bounds__(256) void k_proj(
    const float* __restrict__ x, const float* __restrict__ W,
    const float* __restrict__ bvec, const float* __restrict__ avec,
    uint32* __restrict__ ws)
{
  const int t  = threadIdx.x;
  const int r0 = (int)blockIdx.x * 25;

  __shared__ __align__(16) uint32 xsp[25*68];   // x rows, fp16 f-pairs   6.8 KB
  __shared__ __align__(16) uint32 wcp[80*68];   // W chunk^T fp16        21.8 KB
  __shared__ float wtf[128*41];                 // coalesced f32 staging 21.0 KB

  for (int u = t; u < 25*64; u += 256) {
    int row = u >> 6, f2 = u & 63;
    const float* xp = x + (size_t)(r0+row)*F_ + 2*f2;
    xsp[row*68+f2] = pkh2(xp[0], xp[1]);
  }
  if (blockIdx.x == 0 && t < 100)
    ws[AH_OFF + t] = pkh2(avec[2*t], avec[2*t+1]);

  const int rg = t / 20, cg = t % 20;   // unit (t<140): rows 4rg..+3, cols 4cg..+3 of 80

  for (int c = 0; c < 5; ++c) {
    const int e0 = c * 40;
    // two-pass W staging: half 0 -> W2 (R side, wcp cols 0..39), half 1 -> W1 (cols 40..79)
    for (int half = 0; half < 2; ++half) {
      __syncthreads();                  // consumers of wtf/wcp done
      const float* Wb = W + (half == 0 ? (size_t)F_*E_ : (size_t)0) + e0;
      for (int u = t; u < 128*40; u += 256) {     // coalesced (40-elem runs)
        int f = u / 40, cc = u - f*40;
        wtf[f*41 + cc] = Wb[(size_t)f*E_ + cc];
      }
      __syncthreads();
      for (int u = t; u < 40*64; u += 256) {      // transpose-pack to h2 f-pairs
        int cidx = u >> 6, f2 = u & 63;
        wcp[(half*40 + cidx)*68 + f2] =
            pkh2(wtf[(2*f2)*41 + cidx], wtf[(2*f2+1)*41 + cidx]);
      }
    }
    __syncthreads();
    if (t < 140) {
      float a[4][4];
      #pragma unroll
      for (int r = 0; r < 4; ++r)
        #pragma unroll
        for (int s = 0; s < 4; ++s) a[r][s] = 0.f;
      int rows[4];
      #pragma unroll
      for (int r = 0; r < 4; ++r) rows[r] = (4*rg + r < 25) ? (4*rg + r) : 24;
      #pragma unroll
      for (int q = 0; q < 16; ++q) {
        uint4 xv[4], wv[4];
        #pragma unroll
        for (int r = 0; r < 4; ++r) xv[r] = *(const uint4*)(xsp + rows[r]*68 + 4*q);
        #pragma unroll
        for (int s = 0; s < 4; ++s) wv[s] = *(const uint4*)(wcp + (4*cg+s)*68 + 4*q);
        #pragma unroll
        for (int r = 0; r < 4; ++r)
          #pragma unroll
          for (int s = 0; s < 4; ++s) {
            a[r][s] = FDOT2(bch2(xv[r].x), bch2(wv[s].x), a[r][s]);
            a[r][s] = FDOT2(bch2(xv[r].y), bch2(wv[s].y), a[r][s]);
            a[r][s] = FDOT2(bch2(xv[r].z), bch2(wv[s].z), a[r][s]);
            a[r][s] = FDOT2(bch2(xv[r].w), bch2(wv[s].w), a[r][s]);
          }
      }
      const bool isR  = (cg < 10);
      const int ebase = e0 + (isR ? 4*cg : 4*cg - 40);
      if (isR) {
        #pragma unroll
        for (int s = 0; s < 4; ++s) {
          float bv = bvec[ebase + s];
          #pragma unroll
          for (int r = 0; r < 4; ++r) a[r][s] += bv;
        }
      }
      uint32* dst = ws + (isR ? RH_OFF : LH_OFF);
      #pragma unroll
      for (int r = 0; r < 4; ++r) {
        int row = 4*rg + r;
        if (row < 25) {
          size_t o = (size_t)(r0 + row) * 100 + (ebase >> 1);
          dst[o]   = pkh2(a[r][0], a[r][1]);
          dst[o+1] = pkh2(a[r][2], a[r][3]);
        }
      }
    }
  }
}

// one e-uint (2 e's) of the pair sweep + aL/aR side-dots
#define STEP(lu, au, r0u, r1u, r2u, r3u)                                   \
  do {                                                                     \
    h2 a2 = bch2(au); h2 l2 = bch2(lu); h2 rr, mm;                         \
    al = FDOT2(a2, l2, al);                                                \
    rr = bch2(r0u); ar[0] = FDOT2(a2, rr, ar[0]);                          \
    mm = __builtin_elementwise_min(l2 + rr, z2); acc[0] = FDOT2(a2, mm, acc[0]); \
    rr = bch2(r1u); ar[1] = FDOT2(a2, rr, ar[1]);                          \
    mm = __builtin_elementwise_min(l2 + rr, z2); acc[1] = FDOT2(a2, mm, acc[1]); \
    rr = bch2(r2u); ar[2] = FDOT2(a2, rr, ar[2]);                          \
    mm = __builtin_elementwise_min(l2 + rr, z2); acc[2] = FDOT2(a2, mm, acc[2]); \
    rr = bch2(r3u); ar[3] = FDOT2(a2, rr, ar[3]);                          \
    mm = __builtin_elementwise_min(l2 + rr, z2); acc[3] = FDOT2(a2, mm, acc[3]); \
  } while (0)

// K2: pair sweep (global->regs, NO LDS in hot loop) -> logits -> softmax ->
// h2-att epilogue with global x reads. grid (4 it, 64 b) x 640.
__global__ __launch_bounds__(640) void k_main(
    const float* __restrict__ x, const float* __restrict__ bias,
    const uint32* __restrict__ ws, float* __restrict__ out)
{
  const int t  = threadIdx.x;
  const int i0 = (int)blockIdx.x * 25;
  const int b  = (int)blockIdx.y;

  __shared__ float  att[2500];     // 10 KB
  __shared__ uint32 att2[1250];    //  5 KB
  __shared__ float  scratch[640];
  __shared__ float  rowmax[25], rowinv[25];

  const bool act = (t < 625);
  const int ti = act ? (t % 25) : 0;
  const int tj = act ? (t / 25) : 0;

  const uint32* Lrow = ws + LH_OFF + (size_t)(b*K_ + i0 + ti) * 100;
  const uint32* R0   = ws + RH_OFF + (size_t)(b*K_ + tj) * 100;  // +2500s for row tj+25s
  const uint32* Ap   = ws + AH_OFF;

  float acc[4] = {0.f,0.f,0.f,0.f};
  float ar[4]  = {0.f,0.f,0.f,0.f};
  float al = 0.f;
  h2 z2; z2.x = (half_t)0; z2.y = (half_t)0;

  #pragma unroll
  for (int g = 0; g < 12; ++g) {           // 12 x 8 uints (16 e each)
    const int ba = 8*g;
    uint4 La = *(const uint4*)(Lrow + ba),      Lb = *(const uint4*)(Lrow + ba + 4);
    uint4 Aa = *(const uint4*)(Ap + ba),        Ab = *(const uint4*)(Ap + ba + 4);
    uint4 R0a = *(const uint4*)(R0 + ba),       R0b = *(const uint4*)(R0 + ba + 4);
    uint4 R1a = *(const uint4*)(R0 + 2500+ba),  R1b = *(const uint4*)(R0 + 2500+ba+4);
    uint4 R2a = *(const uint4*)(R0 + 5000+ba),  R2b = *(const uint4*)(R0 + 5000+ba+4);
    uint4 R3a = *(const uint4*)(R0 + 7500+ba),  R3b = *(const uint4*)(R0 + 7500+ba+4);
    STEP(La.x, Aa.x, R0a.x, R1a.x, R2a.x, R3a.x);
    STEP(La.y, Aa.y, R0a.y, R1a.y, R2a.y, R3a.y);
    STEP(La.z, Aa.z, R0a.z, R1a.z, R2a.z, R3a.z);
    STEP(La.w, Aa.w, R0a.w, R1a.w, R2a.w, R3a.w);
    STEP(Lb.x, Ab.x, R0b.x, R1b.x, R2b.x, R3b.x);
    STEP(Lb.y, Ab.y, R0b.y, R1b.y, R2b.y, R3b.y);
    STEP(Lb.z, Ab.z, R0b.z, R1b.z, R2b.z, R3b.z);
    STEP(Lb.w, Ab.w, R0b.w, R1b.w, R2b.w, R3b.w);
  }
  { // tail: uints 96..99
    uint4 La = *(const uint4*)(Lrow + 96);
    uint4 Aa = *(const uint4*)(Ap + 96);
    uint4 R0a = *(const uint4*)(R0 + 96);
    uint4 R1a = *(const uint4*)(R0 + 2596);
    uint4 R2a = *(const uint4*)(R0 + 5096);
    uint4 R3a = *(const uint4*)(R0 + 7596);
    STEP(La.x, Aa.x, R0a.x, R1a.x, R2a.x, R3a.x);
    STEP(La.y, Aa.y, R0a.y, R1a.y, R2a.y, R3a.y);
    STEP(La.z, Aa.z, R0a.z, R1a.z, R2a.z, R3a.z);
    STEP(La.w, Aa.w, R0a.w, R1a.w, R2a.w, R3a.w);
  }

  // logits (clamped -> finite)
  float v[4];
  if (act) {
    #pragma unroll
    for (int s = 0; s < 4; ++s) {
      int j = tj + 25*s;
      float lv = al + ar[s] + bias[(i0 + ti)*K_ + j] - 0.8f*acc[s];
      v[s] = fminf(fmaxf(lv, -30000.f), 30000.f);
    }
  }

  // softmax over j (25 partials per row at threads t%25==ti)
  {
    float m = -3.0e38f;
    if (act) {
      #pragma unroll
      for (int s = 0; s < 4; ++s) m = fmaxf(m, v[s]);
    }
    scratch[t] = m;
    __syncthreads();
    if (t < 25) {
      float mm = scratch[t];
      for (int k = 1; k < 25; ++k) mm = fmaxf(mm, scratch[t + 25*k]);
      rowmax[t] = mm;
    }
    __syncthreads();
    float ssum = 0.f;
    if (act) {
      float m2 = rowmax[ti];
      #pragma unroll
      for (int s = 0; s < 4; ++s) ssum += __expf(v[s] - m2);
    }
    scratch[t] = ssum;
    __syncthreads();
    if (t < 25) {
      float s2 = 0.f;
      for (int k = 0; k < 25; ++k) s2 += scratch[t + 25*k];
      rowinv[t] = 1.f / s2;
    }
    __syncthreads();
  }
  if (act) {
    float m = rowmax[ti], inv = rowinv[ti];
    #pragma unroll
    for (int s = 0; s < 4; ++s)
      att[ti*K_ + tj + 25*s] = __expf(v[s] - m) * inv;
  }
  __syncthreads();
  // pack att -> h2 over j
  for (int u = t; u < 1250; u += 640) {
    int i = u / 50, jp = u - i*50;
    att2[i*50 + jp] = pkh2(att[i*K_ + 2*jp], att[i*K_ + 2*jp + 1]);
  }
  __syncthreads();

  // epilogue: h = sigmoid(att @ x), x from global (coalesced), att2 broadcasts.
  {
    const int f = t & 127, ig = t >> 7;     // ig 0..4 (wave-uniform)
    float z[5];
    #pragma unroll
    for (int m = 0; m < 5; ++m) z[m] = 0.f;
    const float* xb = x + (size_t)b*K_*F_ + f;
    for (int jp = 0; jp < 50; ++jp) {
      float x0 = xb[(size_t)(2*jp)*F_];
      float x1 = xb[(size_t)(2*jp+1)*F_];
      h2 xv = bch2(pkh2(x0, x1));
      #pragma unroll
      for (int m = 0; m < 5; ++m) {
        h2 av = bch2(att2[(ig + 5*m)*50 + jp]);
        z[m] = FDOT2(av, xv, z[m]);
      }
    }
    #pragma unroll
    for (int m = 0; m < 5; ++m) {
      int i = ig + 5*m;
      out[(size_t)(b*K_ + i0 + i)*F_ + f] = 1.f / (1.f + __expf(-z[m]));
    }
  }
}

extern "C" void kernel_launch(void* const* d_in, const int* in_sizes, int n_in,
                              void* d_out, int out_size, void* d_ws, size_t ws_size,
                              hipStream_t stream)
{
  const float* x    = (const float*)d_in[0];   // (64,100,128) f32
  const float* W    = (const float*)d_in[1];   // (256,200) f32
  const float* bvec = (const float*)d_in[2];   // (200,) f32
  const float* avec = (const float*)d_in[3];   // (200,) f32
  const float* bias = (const float*)d_in[4];   // (100,100) f32
  float* out  = (float*)d_out;                 // (64,100,128) f32
  uint32* ws  = (uint32*)d_ws;                 // 5.12 MB used

  k_proj<<<dim3(256), dim3(256), 0, stream>>>(x, W, bvec, avec, ws);
  k_main<<<dim3(4, 64), dim3(640), 0, stream>>>(x, bias, ws, out);
}

// Round 15
// 121.222 us; speedup vs baseline: 1.3911x; 1.0282x over previous
//
#include <hip/hip_runtime.h>

typedef _Float16 half_t;
typedef _Float16 h2 __attribute__((ext_vector_type(2)));
typedef unsigned int uint32;

#define K_ 100
#define F_ 128
#define E_ 200

#if defined(__has_builtin)
#if __has_builtin(__builtin_amdgcn_fdot2)
#define FDOT2(a,b,c) __builtin_amdgcn_fdot2((a),(b),(c),false)
#endif
#endif
#ifndef FDOT2
#define FDOT2(a,b,c) fmaf((float)(a).y,(float)(b).y, fmaf((float)(a).x,(float)(b).x,(c)))
#endif

__device__ __forceinline__ h2 bch2(uint32 u){ return __builtin_bit_cast(h2,u); }
__device__ __forceinline__ uint32 pkh2(float a, float b){
  h2 p; p.x=(half_t)a; p.y=(half_t)b; return __builtin_bit_cast(uint32,p);
}

// ws layout (uints): Lh[6400][100] @0 ; Rh[6400][100] @640000 ; ah2[100] @1280000
#define LH_OFF 0
#define RH_OFF 640000
#define AH_OFF 1280000

// K1 v2: 10 rows/block -> grid 640 (2-3 blocks/CU co-resident vs R14's 1),
// 2x2 fdot2 tiles on 200/256 threads. Latency of one block's staged barriers
// hides behind co-resident blocks' compute.
__global__ __launch_bounds__(256) void k_proj(
    const float* __restrict__ x, const float* __restrict__ W,
    const float* __restrict__ bvec, const float* __restrict__ avec,
    uint32* __restrict__ ws)
{
  const int t  = threadIdx.x;
  const int r0 = (int)blockIdx.x * 10;

  __shared__ __align__(16) uint32 xsp[10*68];   // x rows fp16 f-pairs    2.7 KB
  __shared__ __align__(16) uint32 wcp[80*68];   // W chunk^T fp16        21.8 KB
  __shared__ float wtf[128*41];                 // coalesced f32 staging 21.0 KB

  for (int u = t; u < 10*64; u += 256) {
    int row = u >> 6, f2 = u & 63;
    const float* xp = x + (size_t)(r0+row)*F_ + 2*f2;
    xsp[row*68+f2] = pkh2(xp[0], xp[1]);
  }
  if (blockIdx.x == 0 && t < 100)
    ws[AH_OFF + t] = pkh2(avec[2*t], avec[2*t+1]);

  const int rg  = t / 40;        // 0..4 -> rows 2rg, 2rg+1 (t<200 active)
  const int cp  = t % 40;        // e-pair column within the 80 staged cols
  const bool act = (t < 200);

  for (int c = 0; c < 5; ++c) {
    const int e0 = c * 40;
    // two-pass staging: half 0 -> W2 (R side, wcp rows 0..39), half 1 -> W1 (rows 40..79)
    for (int half = 0; half < 2; ++half) {
      __syncthreads();                  // protect wtf (prev pack) / wcp (prev compute)
      const float* Wb = W + (half == 0 ? (size_t)F_*E_ : (size_t)0) + e0;
      for (int u = t; u < 128*40; u += 256) {     // coalesced (40-elem runs)
        int f = u / 40, cc = u - f*40;
        wtf[f*41 + cc] = Wb[(size_t)f*E_ + cc];
      }
      __syncthreads();
      for (int u = t; u < 40*64; u += 256) {      // transpose-pack to h2 f-pairs
        int cidx = u >> 6, f2 = u & 63;
        wcp[(half*40 + cidx)*68 + f2] =
            pkh2(wtf[(2*f2)*41 + cidx], wtf[(2*f2+1)*41 + cidx]);
      }
    }
    __syncthreads();
    if (act) {
      float a00=0.f, a01=0.f, a10=0.f, a11=0.f;
      const uint32* X0 = xsp + (2*rg)*68;
      const uint32* X1 = X0 + 68;
      const uint32* W0 = wcp + (2*cp)*68;
      const uint32* W1 = W0 + 68;
      #pragma unroll
      for (int q = 0; q < 16; ++q) {
        uint4 x0 = *(const uint4*)(X0 + 4*q);
        uint4 x1 = *(const uint4*)(X1 + 4*q);
        uint4 w0 = *(const uint4*)(W0 + 4*q);
        uint4 w1 = *(const uint4*)(W1 + 4*q);
        a00 = FDOT2(bch2(x0.x),bch2(w0.x),a00); a00 = FDOT2(bch2(x0.y),bch2(w0.y),a00);
        a00 = FDOT2(bch2(x0.z),bch2(w0.z),a00); a00 = FDOT2(bch2(x0.w),bch2(w0.w),a00);
        a01 = FDOT2(bch2(x0.x),bch2(w1.x),a01); a01 = FDOT2(bch2(x0.y),bch2(w1.y),a01);
        a01 = FDOT2(bch2(x0.z),bch2(w1.z),a01); a01 = FDOT2(bch2(x0.w),bch2(w1.w),a01);
        a10 = FDOT2(bch2(x1.x),bch2(w0.x),a10); a10 = FDOT2(bch2(x1.y),bch2(w0.y),a10);
        a10 = FDOT2(bch2(x1.z),bch2(w0.z),a10); a10 = FDOT2(bch2(x1.w),bch2(w0.w),a10);
        a11 = FDOT2(bch2(x1.x),bch2(w1.x),a11); a11 = FDOT2(bch2(x1.y),bch2(w1.y),a11);
        a11 = FDOT2(bch2(x1.z),bch2(w1.z),a11); a11 = FDOT2(bch2(x1.w),bch2(w1.w),a11);
      }
      const bool isR = (cp < 20);
      const int ecol = (isR ? 2*cp : 2*cp - 40);   // local e in [0,40), even
      if (isR) {
        float b0 = bvec[e0 + ecol], b1 = bvec[e0 + ecol + 1];
        a00 += b0; a01 += b1; a10 += b0; a11 += b1;
      }
      uint32* dst = ws + (isR ? RH_OFF : LH_OFF);
      size_t base = (size_t)(r0 + 2*rg) * 100 + ((e0 + ecol) >> 1);
      dst[base]       = pkh2(a00, a01);
      dst[base + 100] = pkh2(a10, a11);
    }
  }
}

// one e-uint (2 e's) of the pair sweep + aL/aR side-dots
#define STEP(lu, au, r0u, r1u, r2u, r3u)                                   \
  do {                                                                     \
    h2 a2 = bch2(au); h2 l2 = bch2(lu); h2 rr, mm;                         \
    al = FDOT2(a2, l2, al);                                                \
    rr = bch2(r0u); ar[0] = FDOT2(a2, rr, ar[0]);                          \
    mm = __builtin_elementwise_min(l2 + rr, z2); acc[0] = FDOT2(a2, mm, acc[0]); \
    rr = bch2(r1u); ar[1] = FDOT2(a2, rr, ar[1]);                          \
    mm = __builtin_elementwise_min(l2 + rr, z2); acc[1] = FDOT2(a2, mm, acc[1]); \
    rr = bch2(r2u); ar[2] = FDOT2(a2, rr, ar[2]);                          \
    mm = __builtin_elementwise_min(l2 + rr, z2); acc[2] = FDOT2(a2, mm, acc[2]); \
    rr = bch2(r3u); ar[3] = FDOT2(a2, rr, ar[3]);                          \
    mm = __builtin_elementwise_min(l2 + rr, z2); acc[3] = FDOT2(a2, mm, acc[3]); \
  } while (0)

// K2: pair sweep (global->regs) -> logits -> softmax -> h2-att epilogue.
// grid (4 it, 64 b) x 640. (unchanged from R14 — clean control)
__global__ __launch_bounds__(640) void k_main(
    const float* __restrict__ x, const float* __restrict__ bias,
    const uint32* __restrict__ ws, float* __restrict__ out)
{
  const int t  = threadIdx.x;
  const int i0 = (int)blockIdx.x * 25;
  const int b  = (int)blockIdx.y;

  __shared__ float  att[2500];
  __shared__ uint32 att2[1250];
  __shared__ float  scratch[640];
  __shared__ float  rowmax[25], rowinv[25];

  const bool act = (t < 625);
  const int ti = act ? (t % 25) : 0;
  const int tj = act ? (t / 25) : 0;

  const uint32* Lrow = ws + LH_OFF + (size_t)(b*K_ + i0 + ti) * 100;
  const uint32* R0   = ws + RH_OFF + (size_t)(b*K_ + tj) * 100;
  const uint32* Ap   = ws + AH_OFF;

  float acc[4] = {0.f,0.f,0.f,0.f};
  float ar[4]  = {0.f,0.f,0.f,0.f};
  float al = 0.f;
  h2 z2; z2.x = (half_t)0; z2.y = (half_t)0;

  #pragma unroll
  for (int g = 0; g < 12; ++g) {
    const int ba = 8*g;
    uint4 La = *(const uint4*)(Lrow + ba),      Lb = *(const uint4*)(Lrow + ba + 4);
    uint4 Aa = *(const uint4*)(Ap + ba),        Ab = *(const uint4*)(Ap + ba + 4);
    uint4 R0a = *(const uint4*)(R0 + ba),       R0b = *(const uint4*)(R0 + ba + 4);
    uint4 R1a = *(const uint4*)(R0 + 2500+ba),  R1b = *(const uint4*)(R0 + 2500+ba+4);
    uint4 R2a = *(const uint4*)(R0 + 5000+ba),  R2b = *(const uint4*)(R0 + 5000+ba+4);
    uint4 R3a = *(const uint4*)(R0 + 7500+ba),  R3b = *(const uint4*)(R0 + 7500+ba+4);
    STEP(La.x, Aa.x, R0a.x, R1a.x, R2a.x, R3a.x);
    STEP(La.y, Aa.y, R0a.y, R1a.y, R2a.y, R3a.y);
    STEP(La.z, Aa.z, R0a.z, R1a.z, R2a.z, R3a.z);
    STEP(La.w, Aa.w, R0a.w, R1a.w, R2a.w, R3a.w);
    STEP(Lb.x, Ab.x, R0b.x, R1b.x, R2b.x, R3b.x);
    STEP(Lb.y, Ab.y, R0b.y, R1b.y, R2b.y, R3b.y);
    STEP(Lb.z, Ab.z, R0b.z, R1b.z, R2b.z, R3b.z);
    STEP(Lb.w, Ab.w, R0b.w, R1b.w, R2b.w, R3b.w);
  }
  {
    uint4 La = *(const uint4*)(Lrow + 96);
    uint4 Aa = *(const uint4*)(Ap + 96);
    uint4 R0a = *(const uint4*)(R0 + 96);
    uint4 R1a = *(const uint4*)(R0 + 2596);
    uint4 R2a = *(const uint4*)(R0 + 5096);
    uint4 R3a = *(const uint4*)(R0 + 7596);
    STEP(La.x, Aa.x, R0a.x, R1a.x, R2a.x, R3a.x);
    STEP(La.y, Aa.y, R0a.y, R1a.y, R2a.y, R3a.y);
    STEP(La.z, Aa.z, R0a.z, R1a.z, R2a.z, R3a.z);
    STEP(La.w, Aa.w, R0a.w, R1a.w, R2a.w, R3a.w);
  }

  float v[4];
  if (act) {
    #pragma unroll
    for (int s = 0; s < 4; ++s) {
      int j = tj + 25*s;
      float lv = al + ar[s] + bias[(i0 + ti)*K_ + j] - 0.8f*acc[s];
      v[s] = fminf(fmaxf(lv, -30000.f), 30000.f);
    }
  }

  {
    float m = -3.0e38f;
    if (act) {
      #pragma unroll
      for (int s = 0; s < 4; ++s) m = fmaxf(m, v[s]);
    }
    scratch[t] = m;
    __syncthreads();
    if (t < 25) {
      float mm = scratch[t];
      for (int k = 1; k < 25; ++k) mm = fmaxf(mm, scratch[t + 25*k]);
      rowmax[t] = mm;
    }
    __syncthreads();
    float ssum = 0.f;
    if (act) {
      float m2 = rowmax[ti];
      #pragma unroll
      for (int s = 0; s < 4; ++s) ssum += __expf(v[s] - m2);
    }
    scratch[t] = ssum;
    __syncthreads();
    if (t < 25) {
      float s2 = 0.f;
      for (int k = 0; k < 25; ++k) s2 += scratch[t + 25*k];
      rowinv[t] = 1.f / s2;
    }
    __syncthreads();
  }
  if (act) {
    float m = rowmax[ti], inv = rowinv[ti];
    #pragma unroll
    for (int s = 0; s < 4; ++s)
      att[ti*K_ + tj + 25*s] = __expf(v[s] - m) * inv;
  }
  __syncthreads();
  for (int u = t; u < 1250; u += 640) {
    int i = u / 50, jp = u - i*50;
    att2[i*50 + jp] = pkh2(att[i*K_ + 2*jp], att[i*K_ + 2*jp + 1]);
  }
  __syncthreads();

  {
    const int f = t & 127, ig = t >> 7;
    float z[5];
    #pragma unroll
    for (int m = 0; m < 5; ++m) z[m] = 0.f;
    const float* xb = x + (size_t)b*K_*F_ + f;
    for (int jp = 0; jp < 50; ++jp) {
      float x0 = xb[(size_t)(2*jp)*F_];
      float x1 = xb[(size_t)(2*jp+1)*F_];
      h2 xv = bch2(pkh2(x0, x1));
      #pragma unroll
      for (int m = 0; m < 5; ++m) {
        h2 av = bch2(att2[(ig + 5*m)*50 + jp]);
        z[m] = FDOT2(av, xv, z[m]);
      }
    }
    #pragma unroll
    for (int m = 0; m < 5; ++m) {
      int i = ig + 5*m;
      out[(size_t)(b*K_ + i0 + i)*F_ + f] = 1.f / (1.f + __expf(-z[m]));
    }
  }
}

extern "C" void kernel_launch(void* const* d_in, const int* in_sizes, int n_in,
                              void* d_out, int out_size, void* d_ws, size_t ws_size,
                              hipStream_t stream)
{
  const float* x    = (const float*)d_in[0];   // (64,100,128) f32
  const float* W    = (const float*)d_in[1];   // (256,200) f32
  const float* bvec = (const float*)d_in[2];   // (200,) f32
  const float* avec = (const float*)d_in[3];   // (200,) f32
  const float* bias = (const float*)d_in[4];   // (100,100) f32
  float* out  = (float*)d_out;                 // (64,100,128) f32
  uint32* ws  = (uint32*)d_ws;                 // 5.12 MB used

  k_proj<<<dim3(640), dim3(256), 0, stream>>>(x, W, bvec, avec, ws);
  k_main<<<dim3(4, 64), dim3(640), 0, stream>>>(x, bias, ws, out);
}